// Round 2
// baseline (562.901 us; speedup 1.0000x reference)
//
#include <hip/hip_runtime.h>
#include <math.h>

#define H      128
#define LNUM   5
#define ONUM   5
#define BATCH  16
#define NPTS   50000
#define TP     128      // points per trunk block (4 waves x 32-POINT slices)
#define XROW   152      // halfs per xs row: 128+24 pad (known-good: b128 reads land 2-way-min)

#define K2LOG2E 2.8853900817779268f   // 2*log2(e): tanh arg -> exp2 arg

typedef _Float16      half8    __attribute__((ext_vector_type(8)));
typedef float         floatx4  __attribute__((ext_vector_type(4)));
typedef unsigned int  uint2v   __attribute__((ext_vector_type(2)));
typedef unsigned int  uint4v   __attribute__((ext_vector_type(4)));
typedef unsigned short ushort8_t __attribute__((ext_vector_type(8)));

static __device__ __forceinline__ unsigned short f2h(float f) {
    _Float16 h = (_Float16)f;                       // v_cvt_f16_f32 (RNE)
    return __builtin_bit_cast(unsigned short, h);
}
static __device__ __forceinline__ unsigned int packh(float a, float b) {
    return (unsigned int)f2h(a) | ((unsigned int)f2h(b) << 16);   // RNE pair
}

// ============ fused branch + weight fold: grid (16, 6), 512 thr (unchanged, known-good) ============
__global__ __launch_bounds__(512)
void fold_kernel(const float* __restrict__ params,
                 const float* __restrict__ bW0, const float* __restrict__ bb0,
                 const float* __restrict__ bWh, const float* __restrict__ bbh,
                 const float* __restrict__ balpha,
                 const float* __restrict__ bWf, const float* __restrict__ bbf,
                 const float* __restrict__ tW0, const float* __restrict__ tb0,
                 const float* __restrict__ tWh, const float* __restrict__ tbh,
                 const float* __restrict__ tWf, const float* __restrict__ talpha,
                 const float* __restrict__ tbf,
                 unsigned short* __restrict__ w0s, unsigned short* __restrict__ whs,
                 unsigned short* __restrict__ wcomb, float* __restrict__ bcomb,
                 float* __restrict__ binit) {
    const int b = blockIdx.x, l = blockIdx.y, t = threadIdx.x;
    __shared__ float hbuf[H];
    __shared__ float Sneed[H];
    __shared__ float pbuf[8];
    __shared__ float zl_sh[ONUM][H];
    if (t < 8) pbuf[t] = params[b * 8 + t];
    __syncthreads();

    float scum = 0.0f;
    if (t < H) {
        float acc = bb0[t];
        for (int k = 0; k < 8; ++k) acc += pbuf[k] * bW0[k * H + t];
        float h = balpha[t] * tanhf(acc);
        hbuf[t] = h;
        scum = h;
        if (l == 0) Sneed[t] = scum;
    }
    for (int i = 1; i < LNUM; ++i) {
        __syncthreads();
        float hn = 0.0f;
        if (t < H) {
            const float* Wl = bWh + (i - 1) * H * H;
            float a2 = bbh[(i - 1) * H + t];
            for (int k = 0; k < H; ++k) a2 += hbuf[k] * Wl[k * H + t];
            hn = balpha[i * H + t] * tanhf(a2);
        }
        __syncthreads();
        if (t < H) {
            hbuf[t] = hn;
            scum += hn;
            if (i == l) Sneed[t] = scum;
        }
    }
    __syncthreads();

    if (l == 5) {
        for (int idx = t; idx < ONUM * H; idx += 512) {
            int o = idx >> 7, hh = idx & 127;
            float z = bbf[o * H + hh];
            for (int k = 0; k < H; ++k) z += hbuf[k] * bWf[k * (H * ONUM) + o * H + hh];
            zl_sh[o][hh] = z;
        }
        __syncthreads();
        for (int j = t; j < 16 * H; j += 512) {
            int o = j >> 7, f = j & 127;
            float v = 0.0f;
            if (o < ONUM) {
                const float* wfr = tWf + f * H;
                float s = 0.0f;
                for (int h = 0; h < H; ++h) s += wfr[h] * zl_sh[o][h];
                v = talpha[4 * H + f] * s;
            }
            wcomb[b * 16 * H + j] = f2h(v);
        }
        if (t < 16) {
            float v = 0.0f;
            if (t < ONUM)
                for (int h = 0; h < H; ++h) v += tbf[h] * zl_sh[t][h];
            bcomb[b * 16 + t] = v;
        }
    } else if (l == 0) {
        if (t < H) binit[(b * LNUM + 0) * H + t] = K2LOG2E * Sneed[t] * tb0[t];
        unsigned int* dst = (unsigned int*)(w0s + b * H * 32);
        for (int j = t; j < H * 16; j += 512) {
            int f = j >> 4, k0 = (j & 15) << 1;
            float s = K2LOG2E * Sneed[f];
            float v0 = (k0 < 3)     ? s * tW0[k0 * H + f]       : 0.0f;
            float v1 = (k0 + 1 < 3) ? s * tW0[(k0 + 1) * H + f] : 0.0f;
            dst[j] = packh(v0, v1);
        }
    } else {
        if (t < H) binit[(b * LNUM + l) * H + t] = K2LOG2E * Sneed[t] * tbh[(l - 1) * H + t];
        const float* Wsrc = tWh + (l - 1) * H * H;
        unsigned int* dst = (unsigned int*)(whs + (b * 4 + (l - 1)) * H * H);
        for (int j = t; j < H * H / 2; j += 512) {
            int f = j >> 6, k0 = (j & 63) << 1;
            float s = K2LOG2E * Sneed[f];
            dst[j] = packh(s * Wsrc[k0 * H + f] * talpha[(l - 1) * H + k0],
                           s * Wsrc[(k0 + 1) * H + f] * talpha[(l - 1) * H + k0 + 1]);
        }
    }
}

// ============ trunk R11: BARRIER-FREE, wave = 32 points x ALL 128 feats ============
// R10 post-mortem: intra-wave MFMA/epilogue interleave never materialized (compiler
// cannot prove xs row-set disjointness -> kept program order); both utils dropped.
// R11 transposes the wave decomposition: wave w owns points [32w,32w+32) and computes
// ALL 128 features for them. Layer l+1's MFMA reads ONLY xs rows the SAME wave wrote
// in layer l's epilogue -> zero cross-wave deps -> NO __syncthreads anywhere.
// Same-wave LDS RAW ordering = compiler lgkmcnt (conservative aliasing is safe here).
// Co-resident waves de-phase freely: one wave's tanh (exp2/rcp) chains fill the VALU
// while others run MFMA/loads. MFMA count per wave unchanged (same 128x32 area).
// LDS B-reads /4 (8 vs 32 b128/layer). Cost: A-frag fetch x4, but all 4 waves/block
// read IDENTICAL addresses (no mq offset) -> L1-served; whs = 2 MB -> L2-resident.
// acc[8][2] = 64 AGPR (same budget as R9); ~128 unified @ launch_bounds(256,3).
__global__ __launch_bounds__(256, 3)
void trunk_kernel(const float* __restrict__ coords,
                  const unsigned short* __restrict__ w0s,
                  const unsigned short* __restrict__ whs,
                  const float* __restrict__ binit,
                  const unsigned short* __restrict__ wcomb,
                  const float* __restrict__ bcomb,
                  float* __restrict__ out) {
    const int b     = blockIdx.y;
    const int n0    = blockIdx.x * TP;
    const int tid   = threadIdx.x;
    const int lane  = tid & 63;
    const int w     = tid >> 6;        // wave 0..3
    const int q     = lane >> 4;       // quad 0..3
    const int c     = lane & 15;
    const int pbase = w * 32;          // wave's private 32-point slice

    __shared__ unsigned short xs[TP * XROW];   // 38912 B; wave w touches rows [32w,32w+32) ONLY

    // ---- stage own 32 points into xs[p][0..31] (fp16, zero-padded K); no barrier ----
    int valid = NPTS - n0; if (valid > TP) valid = TP;
    {
        int p = pbase + (lane >> 1), hh = lane & 1;
        if (hh == 0) {
            float c0 = 0.f, c1 = 0.f, c2 = 0.f;
            if (p < valid) {
                const float* cp = coords + ((size_t)b * NPTS + n0 + p) * 3;
                c0 = cp[0]; c1 = cp[1]; c2 = cp[2];
            }
            uint4v z;
            z.x = __builtin_bit_cast(unsigned int, __builtin_amdgcn_cvt_pkrtz(c0, c1));
            z.y = __builtin_bit_cast(unsigned int, __builtin_amdgcn_cvt_pkrtz(c2, 0.0f));
            z.z = 0; z.w = 0;
            *(uint4v*)&xs[p * XROW + 0] = z;                 // k 0..7
            uint4v zz = {0, 0, 0, 0};
            *(uint4v*)&xs[p * XROW + 8] = zz;                // k 8..15
        } else {
            uint4v zz = {0, 0, 0, 0};
            *(uint4v*)&xs[p * XROW + 16] = zz;               // k 16..31
            *(uint4v*)&xs[p * XROW + 24] = zz;
        }
    }

    floatx4 acc[8][2];   // [mt: feat tile 0..7][nt: point half 0..1]

    // epilogue: tanh (exp2+rcp) + f16 pack + LDS write to OWN rows
    auto epi = [&]() {
        #pragma unroll
        for (int mt = 0; mt < 8; ++mt) {
            int f0 = mt * 16 + q * 4;
            #pragma unroll
            for (int nt = 0; nt < 2; ++nt) {
                int pt = pbase + nt * 16 + c;
                floatx4 v = acc[mt][nt];
                #pragma unroll
                for (int r = 0; r < 4; ++r) {
                    float e  = __builtin_amdgcn_exp2f(v[r]);
                    float rc = __builtin_amdgcn_rcpf(e + 1.0f);
                    v[r] = __builtin_fmaf(-2.0f, rc, 1.0f);             // tanh
                }
                uint2v u;
                u.x = __builtin_bit_cast(unsigned int, __builtin_amdgcn_cvt_pkrtz(v[0], v[1]));
                u.y = __builtin_bit_cast(unsigned int, __builtin_amdgcn_cvt_pkrtz(v[2], v[3]));
                *(uint2v*)&xs[pt * XROW + f0] = u;
            }
        }
    };

    // ================= layer 0: coords (K=32, folded W0), bias via C-operand =================
    {
        const float* bi0 = &binit[(b * LNUM + 0) * H];
        const unsigned short* w0b = w0s + b * H * 32;
        half8 bfr[2];
        #pragma unroll
        for (int nt = 0; nt < 2; ++nt)
            bfr[nt] = __builtin_bit_cast(half8,
                *(const ushort8_t*)&xs[(pbase + nt * 16 + c) * XROW + q * 8]);
        #pragma unroll
        for (int mt = 0; mt < 8; ++mt) {
            half8 af = __builtin_bit_cast(half8,
                *(const ushort8_t*)&w0b[(mt * 16 + c) * 32 + q * 8]);
            floatx4 bi4 = *(const floatx4*)&bi0[mt * 16 + q * 4];
            acc[mt][0] = __builtin_amdgcn_mfma_f32_16x16x32_f16(af, bfr[0], bi4, 0, 0, 0);
            acc[mt][1] = __builtin_amdgcn_mfma_f32_16x16x32_f16(af, bfr[1], bi4, 0, 0, 0);
        }
    }
    epi();

    // ================= hidden layers 1..4 (folded Wh), barrier-free =================
    #pragma unroll
    for (int l = 1; l <= 4; ++l) {
        const unsigned short* wl = whs + (b * 4 + (l - 1)) * H * H;
        const float* bi = &binit[(b * LNUM + l) * H];
        #pragma unroll
        for (int mt = 0; mt < 8; ++mt) {
            floatx4 bi4 = *(const floatx4*)&bi[mt * 16 + q * 4];
            acc[mt][0] = bi4;
            acc[mt][1] = bi4;
        }
        #pragma unroll
        for (int s = 0; s < 4; ++s) {
            half8 bfr[2];
            #pragma unroll
            for (int nt = 0; nt < 2; ++nt)
                bfr[nt] = __builtin_bit_cast(half8,
                    *(const ushort8_t*)&xs[(pbase + nt * 16 + c) * XROW + s * 32 + q * 8]);
            #pragma unroll
            for (int mt = 0; mt < 8; ++mt) {
                half8 af = __builtin_bit_cast(half8,
                    *(const ushort8_t*)&wl[(mt * 16 + c) * H + s * 32 + q * 8]);
                acc[mt][0] = __builtin_amdgcn_mfma_f32_16x16x32_f16(af, bfr[0], acc[mt][0], 0, 0, 0);
                acc[mt][1] = __builtin_amdgcn_mfma_f32_16x16x32_f16(af, bfr[1], acc[mt][1], 0, 0, 0);
            }
        }
        epi();
    }

    // ---- collapsed layer5+einsum: out[b,pt,o] = x4[pt,:] @ Wcomb[o,:] + bcomb[o] ----
    // wave w handles its own pts [32w, 32w+32); reads only own rows -> no barrier
    {
        floatx4 bc = *(const floatx4*)&bcomb[b * 16 + q * 4];
        floatx4 oacc[2] = {bc, bc};
        const unsigned short* wc = wcomb + b * 16 * H;
        #pragma unroll
        for (int s = 0; s < 4; ++s) {
            half8 af = __builtin_bit_cast(half8,
                *(const ushort8_t*)&wc[c * H + s * 32 + q * 8]);
            #pragma unroll
            for (int nt = 0; nt < 2; ++nt) {
                half8 bfr = __builtin_bit_cast(half8,
                    *(const ushort8_t*)&xs[(pbase + nt * 16 + c) * XROW + s * 32 + q * 8]);
                oacc[nt] = __builtin_amdgcn_mfma_f32_16x16x32_f16(af, bfr, oacc[nt], 0, 0, 0);
            }
        }
        #pragma unroll
        for (int nt = 0; nt < 2; ++nt) {
            int pt = n0 + pbase + nt * 16 + c;
            if (pt < NPTS) {
                float* op = out + ((size_t)b * NPTS + pt) * ONUM;
                if (q == 0) {
                    op[0] = oacc[nt][0]; op[1] = oacc[nt][1];
                    op[2] = oacc[nt][2]; op[3] = oacc[nt][3];
                } else if (q == 1) {
                    op[4] = oacc[nt][0];
                }
            }
        }
    }
}

extern "C" void kernel_launch(void* const* d_in, const int* in_sizes, int n_in,
                              void* d_out, int out_size, void* d_ws, size_t ws_size,
                              hipStream_t stream) {
    const float* coords       = (const float*)d_in[0];
    const float* params       = (const float*)d_in[1];
    const float* branch_W0    = (const float*)d_in[2];
    const float* branch_b0    = (const float*)d_in[3];
    const float* branch_Wh    = (const float*)d_in[4];
    const float* branch_bh    = (const float*)d_in[5];
    const float* branch_alpha = (const float*)d_in[6];
    const float* branch_Wf    = (const float*)d_in[7];
    const float* branch_bf    = (const float*)d_in[8];
    const float* trunk_W0     = (const float*)d_in[9];
    const float* trunk_b0     = (const float*)d_in[10];
    const float* trunk_Wh     = (const float*)d_in[11];
    const float* trunk_bh     = (const float*)d_in[12];
    const float* trunk_alpha  = (const float*)d_in[13];
    const float* trunk_Wf     = (const float*)d_in[14];
    const float* trunk_bf     = (const float*)d_in[15];
    float* out = (float*)d_out;

    // workspace layout (256B-aligned offsets)
    char* ws = (char*)d_ws;
    float*          binit = (float*)(ws + 0);                 // 16*5*128 f32   = 40960
    unsigned short* wcomb = (unsigned short*)(ws + 40960);    // 16*16*128 f16  = 65536
    float*          bcomb = (float*)(ws + 106496);            // 16*16 f32      = 1024
    unsigned short* w0s   = (unsigned short*)(ws + 107520);   // 16*128*32 f16  = 131072
    unsigned short* whs   = (unsigned short*)(ws + 238592);   // 16*4*128*128   = 2097152
    // end: 2335744 B

    fold_kernel<<<dim3(BATCH, 6), 512, 0, stream>>>(params, branch_W0, branch_b0,
                                                    branch_Wh, branch_bh, branch_alpha,
                                                    branch_Wf, branch_bf,
                                                    trunk_W0, trunk_b0, trunk_Wh, trunk_bh,
                                                    trunk_Wf, trunk_alpha, trunk_bf,
                                                    w0s, whs, wcomb, bcomb, binit);
    trunk_kernel<<<dim3((NPTS + TP - 1) / TP, BATCH), 256, 0, stream>>>(
        coords, w0s, whs, binit, wcomb, bcomb, out);
}

// Round 3
// 290.907 us; speedup vs baseline: 1.9350x; 1.9350x over previous
//
#include <hip/hip_runtime.h>
#include <math.h>

#define H      128
#define LNUM   5
#define ONUM   5
#define BATCH  16
#define NPTS   50000
#define TP     128      // points per trunk block (4 waves x 32-feat slices)
#define XROW   152      // halfs per xs row: 128+24 pad (known-good: b128 reads land 2-way-min)

#define K2LOG2E 2.8853900817779268f   // 2*log2(e): tanh arg -> exp2 arg

typedef _Float16      half8    __attribute__((ext_vector_type(8)));
typedef float         floatx4  __attribute__((ext_vector_type(4)));
typedef unsigned int  uint2v   __attribute__((ext_vector_type(2)));
typedef unsigned int  uint4v   __attribute__((ext_vector_type(4)));
typedef unsigned short ushort8_t __attribute__((ext_vector_type(8)));

static __device__ __forceinline__ unsigned short f2h(float f) {
    _Float16 h = (_Float16)f;                       // v_cvt_f16_f32 (RNE)
    return __builtin_bit_cast(unsigned short, h);
}
static __device__ __forceinline__ unsigned int packh(float a, float b) {
    return (unsigned int)f2h(a) | ((unsigned int)f2h(b) << 16);   // RNE pair
}

// ============ fused branch + weight fold: grid (16, 6), 512 thr (unchanged, known-good) ============
__global__ __launch_bounds__(512)
void fold_kernel(const float* __restrict__ params,
                 const float* __restrict__ bW0, const float* __restrict__ bb0,
                 const float* __restrict__ bWh, const float* __restrict__ bbh,
                 const float* __restrict__ balpha,
                 const float* __restrict__ bWf, const float* __restrict__ bbf,
                 const float* __restrict__ tW0, const float* __restrict__ tb0,
                 const float* __restrict__ tWh, const float* __restrict__ tbh,
                 const float* __restrict__ tWf, const float* __restrict__ talpha,
                 const float* __restrict__ tbf,
                 unsigned short* __restrict__ w0s, unsigned short* __restrict__ whs,
                 unsigned short* __restrict__ wcomb, float* __restrict__ bcomb,
                 float* __restrict__ binit) {
    const int b = blockIdx.x, l = blockIdx.y, t = threadIdx.x;
    __shared__ float hbuf[H];
    __shared__ float Sneed[H];
    __shared__ float pbuf[8];
    __shared__ float zl_sh[ONUM][H];
    if (t < 8) pbuf[t] = params[b * 8 + t];
    __syncthreads();

    float scum = 0.0f;
    if (t < H) {
        float acc = bb0[t];
        for (int k = 0; k < 8; ++k) acc += pbuf[k] * bW0[k * H + t];
        float h = balpha[t] * tanhf(acc);
        hbuf[t] = h;
        scum = h;
        if (l == 0) Sneed[t] = scum;
    }
    for (int i = 1; i < LNUM; ++i) {
        __syncthreads();
        float hn = 0.0f;
        if (t < H) {
            const float* Wl = bWh + (i - 1) * H * H;
            float a2 = bbh[(i - 1) * H + t];
            for (int k = 0; k < H; ++k) a2 += hbuf[k] * Wl[k * H + t];
            hn = balpha[i * H + t] * tanhf(a2);
        }
        __syncthreads();
        if (t < H) {
            hbuf[t] = hn;
            scum += hn;
            if (i == l) Sneed[t] = scum;
        }
    }
    __syncthreads();

    if (l == 5) {
        for (int idx = t; idx < ONUM * H; idx += 512) {
            int o = idx >> 7, hh = idx & 127;
            float z = bbf[o * H + hh];
            for (int k = 0; k < H; ++k) z += hbuf[k] * bWf[k * (H * ONUM) + o * H + hh];
            zl_sh[o][hh] = z;
        }
        __syncthreads();
        for (int j = t; j < 16 * H; j += 512) {
            int o = j >> 7, f = j & 127;
            float v = 0.0f;
            if (o < ONUM) {
                const float* wfr = tWf + f * H;
                float s = 0.0f;
                for (int h = 0; h < H; ++h) s += wfr[h] * zl_sh[o][h];
                v = talpha[4 * H + f] * s;
            }
            wcomb[b * 16 * H + j] = f2h(v);
        }
        if (t < 16) {
            float v = 0.0f;
            if (t < ONUM)
                for (int h = 0; h < H; ++h) v += tbf[h] * zl_sh[t][h];
            bcomb[b * 16 + t] = v;
        }
    } else if (l == 0) {
        if (t < H) binit[(b * LNUM + 0) * H + t] = K2LOG2E * Sneed[t] * tb0[t];
        unsigned int* dst = (unsigned int*)(w0s + b * H * 32);
        for (int j = t; j < H * 16; j += 512) {
            int f = j >> 4, k0 = (j & 15) << 1;
            float s = K2LOG2E * Sneed[f];
            float v0 = (k0 < 3)     ? s * tW0[k0 * H + f]       : 0.0f;
            float v1 = (k0 + 1 < 3) ? s * tW0[(k0 + 1) * H + f] : 0.0f;
            dst[j] = packh(v0, v1);
        }
    } else {
        if (t < H) binit[(b * LNUM + l) * H + t] = K2LOG2E * Sneed[t] * tbh[(l - 1) * H + t];
        const float* Wsrc = tWh + (l - 1) * H * H;
        unsigned int* dst = (unsigned int*)(whs + (b * 4 + (l - 1)) * H * H);
        for (int j = t; j < H * H / 2; j += 512) {
            int f = j >> 6, k0 = (j & 63) << 1;
            float s = K2LOG2E * Sneed[f];
            dst[j] = packh(s * Wsrc[k0 * H + f] * talpha[(l - 1) * H + k0],
                           s * Wsrc[(k0 + 1) * H + f] * talpha[(l - 1) * H + k0 + 1]);
        }
    }
}

// ============ trunk R12: R9 schedule (known-good 197us) + 2 instruction-count cuts ============
// R10 (chunk-split pipeline) and R11 (barrier-free point-slice) both regressed:
// rescheduling loses more than overlap gains. R9 structure restored EXACTLY.
// R12 changes (both local, math-identical):
//   (1) bias fused into MFMA C-operand at the first K-slice of every layer
//       -> deletes 64 acc-init moves/layer/wave (~320 VALU inst/wave, ~6% of VALU work).
//   (2) s_setprio(1) around each layer's MFMA region (T5): 3 de-phased blocks/CU put
//       some waves in MFMA phase while others run tanh epilogues; priority keeps the
//       matrix pipe fed out of the shared issue port.
// acc[2][8] = 64 AGPR; unified ~124 fits the 170-reg budget of 3 waves/EU.
// (64-AGPR tiles spill at the 128 budget of 4 waves/EU -- R3/R5.)
// ALL barriers are __syncthreads (R9: hand-rolled s_barrier raced).
__global__ __launch_bounds__(256, 3)
void trunk_kernel(const float* __restrict__ coords,
                  const unsigned short* __restrict__ w0s,
                  const unsigned short* __restrict__ whs,
                  const float* __restrict__ binit,
                  const unsigned short* __restrict__ wcomb,
                  const float* __restrict__ bcomb,
                  float* __restrict__ out) {
    const int b    = blockIdx.y;
    const int n0   = blockIdx.x * TP;
    const int tid  = threadIdx.x;
    const int lane = tid & 63;
    const int w    = tid >> 6;        // wave 0..3
    const int q    = lane >> 4;       // quad 0..3
    const int c    = lane & 15;
    const int mq   = w * 32;          // wave's feature quarter (M); every wave covers all 128 pts

    __shared__ unsigned short xs[TP * XROW];   // 38912 B -> 3 blocks/CU (VGPR-bound)

    // ---- stage coords into xs[p][0..31] (fp16, zero-padded K) ----
    int valid = NPTS - n0; if (valid > TP) valid = TP;
    {
        int p = tid >> 1, hh = tid & 1;
        if (hh == 0) {
            float c0 = 0.f, c1 = 0.f, c2 = 0.f;
            if (p < valid) {
                const float* cp = coords + ((size_t)b * NPTS + n0 + p) * 3;
                c0 = cp[0]; c1 = cp[1]; c2 = cp[2];
            }
            uint4v z;
            z.x = __builtin_bit_cast(unsigned int, __builtin_amdgcn_cvt_pkrtz(c0, c1));
            z.y = __builtin_bit_cast(unsigned int, __builtin_amdgcn_cvt_pkrtz(c2, 0.0f));
            z.z = 0; z.w = 0;
            *(uint4v*)&xs[p * XROW + 0] = z;                 // k 0..7
            uint4v zz = {0, 0, 0, 0};
            *(uint4v*)&xs[p * XROW + 8] = zz;                // k 8..15
        } else {
            uint4v zz = {0, 0, 0, 0};
            *(uint4v*)&xs[p * XROW + 16] = zz;               // k 16..31
            *(uint4v*)&xs[p * XROW + 24] = zz;
        }
    }
    __syncthreads();

    floatx4 acc[2][8];

    // ================= layer 0: coords (K=32, folded W0), bias via C-operand =================
    {
        const unsigned short* w0b = w0s + b * H * 32;
        const float* bi0 = &binit[(b * LNUM + 0) * H];
        half8 af[2];
        floatx4 bi4[2];
        #pragma unroll
        for (int mt = 0; mt < 2; ++mt) {
            af[mt] = __builtin_bit_cast(half8,
                *(const ushort8_t*)&w0b[(mq + mt * 16 + c) * 32 + q * 8]);
            bi4[mt] = *(const floatx4*)&bi0[mq + mt * 16 + q * 4];
        }
        __builtin_amdgcn_s_setprio(1);
        #pragma unroll
        for (int nt = 0; nt < 8; ++nt) {
            half8 bfr = __builtin_bit_cast(half8,
                *(const ushort8_t*)&xs[(nt * 16 + c) * XROW + q * 8]);
            #pragma unroll
            for (int mt = 0; mt < 2; ++mt)
                acc[mt][nt] = __builtin_amdgcn_mfma_f32_16x16x32_f16(af[mt], bfr, bi4[mt], 0, 0, 0);
        }
        __builtin_amdgcn_s_setprio(0);
    }
    __syncthreads();
    // ---- epilogue layer 0: acc already = 2log2e*S*(Wx+b) ----
    #pragma unroll
    for (int mt = 0; mt < 2; ++mt) {
        int f0 = mq + mt * 16 + q * 4;
        #pragma unroll
        for (int nt = 0; nt < 8; ++nt) {
            int pt = nt * 16 + c;
            floatx4 v = acc[mt][nt];
            #pragma unroll
            for (int r = 0; r < 4; ++r) {
                float e  = __builtin_amdgcn_exp2f(v[r]);
                float rc = __builtin_amdgcn_rcpf(e + 1.0f);
                v[r] = __builtin_fmaf(-2.0f, rc, 1.0f);             // tanh
            }
            uint2v u;
            u.x = __builtin_bit_cast(unsigned int, __builtin_amdgcn_cvt_pkrtz(v[0], v[1]));
            u.y = __builtin_bit_cast(unsigned int, __builtin_amdgcn_cvt_pkrtz(v[2], v[3]));
            *(uint2v*)&xs[pt * XROW + f0] = u;
        }
    }

    // ================= hidden layers 1..4 (folded Wh) =================
    for (int l = 1; l <= 4; ++l) {
        const unsigned short* wl = whs + (b * 4 + (l - 1)) * H * H;
        const float* bi = &binit[(b * LNUM + l) * H];
        floatx4 bi4[2];
        #pragma unroll
        for (int mt = 0; mt < 2; ++mt)
            bi4[mt] = *(const floatx4*)&bi[mq + mt * 16 + q * 4];
        __syncthreads();                          // prev epilogue writes visible
        __builtin_amdgcn_s_setprio(1);
        #pragma unroll
        for (int s = 0; s < 4; ++s) {
            half8 af[2];
            #pragma unroll
            for (int mt = 0; mt < 2; ++mt)
                af[mt] = __builtin_bit_cast(half8,
                    *(const ushort8_t*)&wl[(mq + mt * 16 + c) * H + s * 32 + q * 8]);
            #pragma unroll
            for (int nt = 0; nt < 8; ++nt) {
                half8 bfr = __builtin_bit_cast(half8,
                    *(const ushort8_t*)&xs[(nt * 16 + c) * XROW + s * 32 + q * 8]);
                if (s == 0) {
                    #pragma unroll
                    for (int mt = 0; mt < 2; ++mt)
                        acc[mt][nt] = __builtin_amdgcn_mfma_f32_16x16x32_f16(af[mt], bfr, bi4[mt], 0, 0, 0);
                } else {
                    #pragma unroll
                    for (int mt = 0; mt < 2; ++mt)
                        acc[mt][nt] = __builtin_amdgcn_mfma_f32_16x16x32_f16(af[mt], bfr, acc[mt][nt], 0, 0, 0);
                }
            }
        }
        __builtin_amdgcn_s_setprio(0);
        __syncthreads();                          // all xs reads done before overwrite
        #pragma unroll
        for (int mt = 0; mt < 2; ++mt) {
            int f0 = mq + mt * 16 + q * 4;
            #pragma unroll
            for (int nt = 0; nt < 8; ++nt) {
                int pt = nt * 16 + c;
                floatx4 v = acc[mt][nt];
                #pragma unroll
                for (int r = 0; r < 4; ++r) {
                    float e  = __builtin_amdgcn_exp2f(v[r]);
                    float rc = __builtin_amdgcn_rcpf(e + 1.0f);
                    v[r] = __builtin_fmaf(-2.0f, rc, 1.0f);
                }
                uint2v u;
                u.x = __builtin_bit_cast(unsigned int, __builtin_amdgcn_cvt_pkrtz(v[0], v[1]));
                u.y = __builtin_bit_cast(unsigned int, __builtin_amdgcn_cvt_pkrtz(v[2], v[3]));
                *(uint2v*)&xs[pt * XROW + f0] = u;
            }
        }
    }
    __syncthreads();                              // x4 (tanh) ready in xs

    // ---- collapsed layer5+einsum: out[b,pt,o] = x4[pt,:] @ Wcomb[o,:] + bcomb[o] ----
    // wave w handles pts [32w, 32w+32)
    {
        floatx4 bc = *(const floatx4*)&bcomb[b * 16 + q * 4];
        floatx4 oacc[2];
        const unsigned short* wc = wcomb + b * 16 * H;
        #pragma unroll
        for (int s = 0; s < 4; ++s) {
            half8 af = __builtin_bit_cast(half8,
                *(const ushort8_t*)&wc[c * H + s * 32 + q * 8]);
            #pragma unroll
            for (int nt = 0; nt < 2; ++nt) {
                half8 bfr = __builtin_bit_cast(half8,
                    *(const ushort8_t*)&xs[(w * 32 + nt * 16 + c) * XROW + s * 32 + q * 8]);
                if (s == 0)
                    oacc[nt] = __builtin_amdgcn_mfma_f32_16x16x32_f16(af, bfr, bc, 0, 0, 0);
                else
                    oacc[nt] = __builtin_amdgcn_mfma_f32_16x16x32_f16(af, bfr, oacc[nt], 0, 0, 0);
            }
        }
        #pragma unroll
        for (int nt = 0; nt < 2; ++nt) {
            int pt = n0 + w * 32 + nt * 16 + c;
            if (pt < NPTS) {
                float* op = out + ((size_t)b * NPTS + pt) * ONUM;
                if (q == 0) {
                    op[0] = oacc[nt][0]; op[1] = oacc[nt][1];
                    op[2] = oacc[nt][2]; op[3] = oacc[nt][3];
                } else if (q == 1) {
                    op[4] = oacc[nt][0];
                }
            }
        }
    }
}

extern "C" void kernel_launch(void* const* d_in, const int* in_sizes, int n_in,
                              void* d_out, int out_size, void* d_ws, size_t ws_size,
                              hipStream_t stream) {
    const float* coords       = (const float*)d_in[0];
    const float* params       = (const float*)d_in[1];
    const float* branch_W0    = (const float*)d_in[2];
    const float* branch_b0    = (const float*)d_in[3];
    const float* branch_Wh    = (const float*)d_in[4];
    const float* branch_bh    = (const float*)d_in[5];
    const float* branch_alpha = (const float*)d_in[6];
    const float* branch_Wf    = (const float*)d_in[7];
    const float* branch_bf    = (const float*)d_in[8];
    const float* trunk_W0     = (const float*)d_in[9];
    const float* trunk_b0     = (const float*)d_in[10];
    const float* trunk_Wh     = (const float*)d_in[11];
    const float* trunk_bh     = (const float*)d_in[12];
    const float* trunk_alpha  = (const float*)d_in[13];
    const float* trunk_Wf     = (const float*)d_in[14];
    const float* trunk_bf     = (const float*)d_in[15];
    float* out = (float*)d_out;

    // workspace layout (256B-aligned offsets)
    char* ws = (char*)d_ws;
    float*          binit = (float*)(ws + 0);                 // 16*5*128 f32   = 40960
    unsigned short* wcomb = (unsigned short*)(ws + 40960);    // 16*16*128 f16  = 65536
    float*          bcomb = (float*)(ws + 106496);            // 16*16 f32      = 1024
    unsigned short* w0s   = (unsigned short*)(ws + 107520);   // 16*128*32 f16  = 131072
    unsigned short* whs   = (unsigned short*)(ws + 238592);   // 16*4*128*128   = 2097152
    // end: 2335744 B

    fold_kernel<<<dim3(BATCH, 6), 512, 0, stream>>>(params, branch_W0, branch_b0,
                                                    branch_Wh, branch_bh, branch_alpha,
                                                    branch_Wf, branch_bf,
                                                    trunk_W0, trunk_b0, trunk_Wh, trunk_bh,
                                                    trunk_Wf, trunk_alpha, trunk_bf,
                                                    w0s, whs, wcomb, bcomb, binit);
    trunk_kernel<<<dim3((NPTS + TP - 1) / TP, BATCH), 256, 0, stream>>>(
        coords, w0s, whs, binit, wcomb, bcomb, out);
}